// Round 1
// baseline (1942.346 us; speedup 1.0000x reference)
//
#include <hip/hip_runtime.h>
#include <math.h>

#define N_NODES 100000
#define D_DIM   64
#define N_EDGES 1600000
#define P_L 0.5f
#define P_H 0.5f

// out[n][i] = br[i]  (d_out is re-poisoned before every launch)
__global__ __launch_bounds__(256) void init_out_kernel(float* __restrict__ out,
                                                       const float* __restrict__ br,
                                                       int total) {
    int idx = blockIdx.x * 256 + threadIdx.x;
    if (idx < total) out[idx] = br[idx & 63];
}

// One wave per node:
//  - 4 gate dot-products (Wl/Wh halves) via shuffle butterfly
//  - u_low[n]  = Wr[:, :64] . h[n]   (per-lane output element, Wr transposed in LDS)
//  - u_high[n] = Wr[:, 64:] . h[n]
__global__ __launch_bounds__(256) void node_proj_kernel(
    const float* __restrict__ h,
    const float* __restrict__ Wl,
    const float* __restrict__ Wh,
    const float* __restrict__ Wr,
    float* __restrict__ u_low,  float* __restrict__ u_high,
    float* __restrict__ gl_dst, float* __restrict__ gl_src,
    float* __restrict__ gh_dst, float* __restrict__ gh_src)
{
    // Wr is [64 rows][128 cols]; store two transposed 64x64 tiles:
    // wrt_low[j*64+i] = Wr[i][j], wrt_high[j*64+i] = Wr[i][64+j]
    __shared__ float wrt_low [64 * 64];
    __shared__ float wrt_high[64 * 64];

    int tid = threadIdx.x;
    for (int idx = tid; idx < 64 * 128; idx += 256) {
        int i = idx >> 7;        // row of Wr
        int j = idx & 127;       // col of Wr
        float v = Wr[idx];
        if (j < 64) wrt_low [j * 64 + i] = v;
        else        wrt_high[(j - 64) * 64 + i] = v;
    }
    __syncthreads();

    int wave = tid >> 6;
    int lane = tid & 63;
    int node = blockIdx.x * 4 + wave;
    if (node >= N_NODES) return;

    float hval = h[node * 64 + lane];

    // gate partial products
    float pld = hval * Wl[lane];
    float pls = hval * Wl[64 + lane];
    float phd = hval * Wh[lane];
    float phs = hval * Wh[64 + lane];
    #pragma unroll
    for (int m = 32; m >= 1; m >>= 1) {
        pld += __shfl_xor(pld, m);
        pls += __shfl_xor(pls, m);
        phd += __shfl_xor(phd, m);
        phs += __shfl_xor(phs, m);
    }
    if (lane == 0) {
        gl_dst[node] = pld;
        gl_src[node] = pls;
        gh_dst[node] = phd;
        gh_src[node] = phs;
    }

    // u projections: lane i accumulates output element i
    float ul = 0.f, uh = 0.f;
    #pragma unroll
    for (int j = 0; j < 64; ++j) {
        float hb = __shfl(hval, j);               // constant lane -> v_readlane
        ul += wrt_low [j * 64 + lane] * hb;       // lane-consecutive: conflict-free
        uh += wrt_high[j * 64 + lane] * hb;
    }
    u_low [node * 64 + lane] = ul;
    u_high[node * 64 + lane] = uh;
}

// 4 edges per wave; each 16-lane group handles one edge, each lane a float4 slice.
__global__ __launch_bounds__(256) void edge_kernel(
    const int* __restrict__ src, const int* __restrict__ dst,
    const float* __restrict__ dvec,
    const float* __restrict__ gl_dst, const float* __restrict__ gl_src,
    const float* __restrict__ gh_dst, const float* __restrict__ gh_src,
    const float* __restrict__ u_low, const float* __restrict__ u_high,
    const float* __restrict__ bl, const float* __restrict__ bh,
    float* __restrict__ out)
{
    int gtid = blockIdx.x * 256 + threadIdx.x;
    int e = gtid >> 4;
    if (e >= N_EDGES) return;
    int elem = (gtid & 15) * 4;

    int s = src[e];
    int t = dst[e];

    float xl = gl_dst[t] + gl_src[s] + bl[0];
    float xh = gh_dst[t] + gh_src[s] + bh[0];
    float ll = xl > 0.f ? xl : -P_L * xl;   // leaky gate, always >= 0 (relu is no-op)
    float hhv = xh > 0.f ? xh : -P_H * xh;
    float dd = dvec[t] * dvec[s];
    float el =  tanhf(ll)  * dd;
    float eh = -tanhf(hhv) * dd;

    const float4 ul4 = *(const float4*)(u_low  + (size_t)s * 64 + elem);
    const float4 uh4 = *(const float4*)(u_high + (size_t)s * 64 + elem);

    float* op = out + (size_t)t * 64 + elem;
    unsafeAtomicAdd(op + 0, el * ul4.x + eh * uh4.x);
    unsafeAtomicAdd(op + 1, el * ul4.y + eh * uh4.y);
    unsafeAtomicAdd(op + 2, el * ul4.z + eh * uh4.z);
    unsafeAtomicAdd(op + 3, el * ul4.w + eh * uh4.w);
}

extern "C" void kernel_launch(void* const* d_in, const int* in_sizes, int n_in,
                              void* d_out, int out_size, void* d_ws, size_t ws_size,
                              hipStream_t stream) {
    const float* h    = (const float*)d_in[0];
    const float* dvec = (const float*)d_in[1];
    const int*   src  = (const int*)  d_in[2];
    const int*   dst  = (const int*)  d_in[3];
    const float* Wl   = (const float*)d_in[4];
    const float* bl   = (const float*)d_in[5];
    const float* Wh   = (const float*)d_in[6];
    const float* bh   = (const float*)d_in[7];
    const float* Wr   = (const float*)d_in[8];
    const float* br   = (const float*)d_in[9];
    float* out = (float*)d_out;

    float* ws = (float*)d_ws;
    float* u_low  = ws;                                   // N*64
    float* u_high = ws + (size_t)N_NODES * 64;            // N*64
    float* gl_dst = ws + (size_t)N_NODES * 128;           // N
    float* gl_src = gl_dst + N_NODES;                     // N
    float* gh_dst = gl_src + N_NODES;                     // N
    float* gh_src = gh_dst + N_NODES;                     // N

    int total_out = N_NODES * D_DIM;
    init_out_kernel<<<(total_out + 255) / 256, 256, 0, stream>>>(out, br, total_out);

    node_proj_kernel<<<(N_NODES + 3) / 4, 256, 0, stream>>>(
        h, Wl, Wh, Wr, u_low, u_high, gl_dst, gl_src, gh_dst, gh_src);

    edge_kernel<<<(N_EDGES * 16 + 255) / 256, 256, 0, stream>>>(
        src, dst, dvec, gl_dst, gl_src, gh_dst, gh_src, u_low, u_high, bl, bh, out);
}

// Round 2
// 476.399 us; speedup vs baseline: 4.0771x; 4.0771x over previous
//
#include <hip/hip_runtime.h>
#include <math.h>

#define N_NODES 100000
#define D_DIM   64
#define N_EDGES 1600000
#define P_L 0.5f
#define P_H 0.5f

// ---------------------------------------------------------------------------
// K0: zero the degree-count array (workspace is poisoned before every launch)
// ---------------------------------------------------------------------------
__global__ __launch_bounds__(256) void zero_counts_kernel(int* __restrict__ count) {
    int i = blockIdx.x * 256 + threadIdx.x;
    if (i < N_NODES) count[i] = 0;
}

// ---------------------------------------------------------------------------
// K1: node projections. One thread per node, h-row in 64 VGPRs,
// Wr broadcast from LDS via float4 same-address reads.
//   u_low[n][c]  = sum_k h[n][k] * Wr[c][k]        (c in 0..63)
//   u_high[n][c] = sum_k h[n][k] * Wr[c][64+k]
//   g4[n] = { h.Wl[:64], h.Wl[64:], h.Wh[:64], h.Wh[64:] }
// Wr input layout is [64 rows c][128 cols k].
// ---------------------------------------------------------------------------
__global__ __launch_bounds__(256) void node_proj_kernel(
    const float* __restrict__ h,
    const float* __restrict__ Wl,
    const float* __restrict__ Wh,
    const float* __restrict__ Wr,
    float* __restrict__ u_low, float* __restrict__ u_high,
    float4* __restrict__ g4)
{
    // wr_lds[k][c]: transposed so the 16-col output chunk is contiguous per k.
    // wr_lds[k*128 + c] = Wr[c*128... wait: we need, for output col c, the
    // weight Wr[c][k] (low) and Wr[c][64+k] (high). Store:
    //   wr_lds[k*128 + c]      = Wr[c][k]       (c in 0..63)
    //   wr_lds[k*128 + 64 + c] = Wr[c][64 + k]  (c in 0..63)
    // so for fixed k, cols 0..127 are contiguous: chunk reads are float4.
    __shared__ float wr_lds[64 * 128];
    __shared__ float4 gw_lds[64];   // {Wl[k], Wl[64+k], Wh[k], Wh[64+k]}

    int tid = threadIdx.x;
    for (int idx = tid; idx < 64 * 128; idx += 256) {
        int c = idx >> 7;          // row of Wr (output col), 0..63
        int j = idx & 127;         // col of Wr (input k), 0..127
        float v = Wr[idx];
        if (j < 64) wr_lds[j * 128 + c] = v;
        else        wr_lds[(j - 64) * 128 + 64 + c] = v;
    }
    for (int k = tid; k < 64; k += 256)
        gw_lds[k] = make_float4(Wl[k], Wl[64 + k], Wh[k], Wh[64 + k]);
    __syncthreads();

    int node = blockIdx.x * 256 + tid;
    if (node >= N_NODES) return;

    // h row into registers
    float hreg[64];
    const float4* hp = (const float4*)(h + (size_t)node * 64);
    #pragma unroll
    for (int q = 0; q < 16; ++q) {
        float4 v = hp[q];
        hreg[4 * q + 0] = v.x; hreg[4 * q + 1] = v.y;
        hreg[4 * q + 2] = v.z; hreg[4 * q + 3] = v.w;
    }

    // gate projections
    float gld = 0.f, gls = 0.f, ghd = 0.f, ghs = 0.f;
    #pragma unroll
    for (int k = 0; k < 64; ++k) {
        float4 g = gw_lds[k];
        gld += hreg[k] * g.x;
        gls += hreg[k] * g.y;
        ghd += hreg[k] * g.z;
        ghs += hreg[k] * g.w;
    }
    g4[node] = make_float4(gld, gls, ghd, ghs);

    // u projections in chunks of 16 output columns
    for (int c0 = 0; c0 < 128; c0 += 16) {
        float acc[16];
        #pragma unroll
        for (int j = 0; j < 16; ++j) acc[j] = 0.f;
        #pragma unroll
        for (int k = 0; k < 64; ++k) {
            const float* wrow = &wr_lds[k * 128 + c0];
            float4 w0 = *(const float4*)(wrow + 0);
            float4 w1 = *(const float4*)(wrow + 4);
            float4 w2 = *(const float4*)(wrow + 8);
            float4 w3 = *(const float4*)(wrow + 12);
            float hv = hreg[k];
            acc[0]  += hv * w0.x; acc[1]  += hv * w0.y; acc[2]  += hv * w0.z; acc[3]  += hv * w0.w;
            acc[4]  += hv * w1.x; acc[5]  += hv * w1.y; acc[6]  += hv * w1.z; acc[7]  += hv * w1.w;
            acc[8]  += hv * w2.x; acc[9]  += hv * w2.y; acc[10] += hv * w2.z; acc[11] += hv * w2.w;
            acc[12] += hv * w3.x; acc[13] += hv * w3.y; acc[14] += hv * w3.z; acc[15] += hv * w3.w;
        }
        float* dstp = (c0 < 64) ? (u_low  + (size_t)node * 64 + c0)
                                : (u_high + (size_t)node * 64 + (c0 - 64));
        #pragma unroll
        for (int q = 0; q < 4; ++q) {
            *(float4*)(dstp + 4 * q) = make_float4(acc[4*q], acc[4*q+1], acc[4*q+2], acc[4*q+3]);
        }
    }
}

// ---------------------------------------------------------------------------
// K2: histogram of dst
// ---------------------------------------------------------------------------
__global__ __launch_bounds__(256) void hist_kernel(const int* __restrict__ dst,
                                                   int* __restrict__ count) {
    int e = blockIdx.x * 256 + threadIdx.x;
    if (e < N_EDGES) atomicAdd(&count[dst[e]], 1);
}

// ---------------------------------------------------------------------------
// K3a: per-256-chunk sums
// ---------------------------------------------------------------------------
__global__ __launch_bounds__(256) void chunk_sum_kernel(const int* __restrict__ count,
                                                        int* __restrict__ chunksum) {
    __shared__ int sdata[256];
    int t = threadIdx.x;
    int i = blockIdx.x * 256 + t;
    int v = (i < N_NODES) ? count[i] : 0;
    sdata[t] = v;
    __syncthreads();
    #pragma unroll
    for (int s = 128; s >= 1; s >>= 1) {
        if (t < s) sdata[t] += sdata[t + s];
        __syncthreads();
    }
    if (t == 0) chunksum[blockIdx.x] = sdata[0];
}

// ---------------------------------------------------------------------------
// K3b: exclusive scan of chunk sums (<=512 chunks), single block
// ---------------------------------------------------------------------------
#define N_CHUNKS ((N_NODES + 255) / 256)
__global__ __launch_bounds__(512) void chunk_scan_kernel(const int* __restrict__ chunksum,
                                                         int* __restrict__ chunkbase) {
    __shared__ int sdata[512];
    int t = threadIdx.x;
    int v = (t < N_CHUNKS) ? chunksum[t] : 0;
    sdata[t] = v;
    __syncthreads();
    #pragma unroll
    for (int d = 1; d < 512; d <<= 1) {
        int x = (t >= d) ? sdata[t - d] : 0;
        __syncthreads();
        sdata[t] += x;
        __syncthreads();
    }
    if (t < N_CHUNKS) chunkbase[t] = sdata[t] - v;   // exclusive
}

// ---------------------------------------------------------------------------
// K3c: local exclusive scan per chunk + base -> offs, cursor
// ---------------------------------------------------------------------------
__global__ __launch_bounds__(256) void local_scan_kernel(const int* __restrict__ count,
                                                         const int* __restrict__ chunkbase,
                                                         int* __restrict__ offs,
                                                         int* __restrict__ cursor) {
    __shared__ int sdata[256];
    int t = threadIdx.x;
    int i = blockIdx.x * 256 + t;
    int v = (i < N_NODES) ? count[i] : 0;
    sdata[t] = v;
    __syncthreads();
    #pragma unroll
    for (int d = 1; d < 256; d <<= 1) {
        int x = (t >= d) ? sdata[t - d] : 0;
        __syncthreads();
        sdata[t] += x;
        __syncthreads();
    }
    int excl = chunkbase[blockIdx.x] + sdata[t] - v;
    if (i < N_NODES) {
        offs[i] = excl;
        cursor[i] = excl;
        if (i == N_NODES - 1) offs[N_NODES] = excl + v;
    }
}

// ---------------------------------------------------------------------------
// K4: scatter edge -> CSR slot (store src id only; gates computed in gather)
// ---------------------------------------------------------------------------
__global__ __launch_bounds__(256) void scatter_kernel(const int* __restrict__ src,
                                                      const int* __restrict__ dst,
                                                      int* __restrict__ cursor,
                                                      int* __restrict__ esrc) {
    int e = blockIdx.x * 256 + threadIdx.x;
    if (e >= N_EDGES) return;
    int t = dst[e];
    int pos = atomicAdd(&cursor[t], 1);
    esrc[pos] = src[e];
}

// ---------------------------------------------------------------------------
// K5: gather. One wave per dst node; 4 subgroups of 16 lanes each take one
// edge per iteration; each lane owns a float4 slice of the 64 output dims.
// ---------------------------------------------------------------------------
__global__ __launch_bounds__(256) void gather_kernel(
    const int* __restrict__ offs,
    const int* __restrict__ esrc,
    const float4* __restrict__ g4,
    const float* __restrict__ dvec,
    const float* __restrict__ u_low, const float* __restrict__ u_high,
    const float* __restrict__ bl, const float* __restrict__ bh,
    const float* __restrict__ br,
    float* __restrict__ out)
{
    int tid = threadIdx.x;
    int node = blockIdx.x * 4 + (tid >> 6);
    if (node >= N_NODES) return;
    int lane = tid & 63;
    int sub = lane >> 4;        // 0..3: edge slot within wave
    int l16 = lane & 15;        // float4 slice index

    int beg = offs[node];
    int end = offs[node + 1];

    float4 gt = g4[node];
    float dt = dvec[node];
    float bl0 = bl[0];
    float bh0 = bh[0];

    float4 acc = make_float4(0.f, 0.f, 0.f, 0.f);

    for (int k = beg + sub; k < end; k += 4) {
        int s = esrc[k];
        float4 gs = g4[s];
        float xl = gt.x + gs.y + bl0;
        float xh = gt.z + gs.w + bh0;
        float ll = xl > 0.f ? xl : -P_L * xl;     // leaky, always >= 0
        float hh = xh > 0.f ? xh : -P_H * xh;
        float dd = dt * dvec[s];
        float el =  tanhf(ll) * dd;
        float eh = -tanhf(hh) * dd;

        const float4 ul = *(const float4*)(u_low  + (size_t)s * 64 + l16 * 4);
        const float4 uh = *(const float4*)(u_high + (size_t)s * 64 + l16 * 4);
        acc.x += el * ul.x + eh * uh.x;
        acc.y += el * ul.y + eh * uh.y;
        acc.z += el * ul.z + eh * uh.z;
        acc.w += el * ul.w + eh * uh.w;
    }

    // fold the 4 subgroups (same l16 -> same columns)
    #pragma unroll
    for (int m = 16; m <= 32; m <<= 1) {
        acc.x += __shfl_xor(acc.x, m);
        acc.y += __shfl_xor(acc.y, m);
        acc.z += __shfl_xor(acc.z, m);
        acc.w += __shfl_xor(acc.w, m);
    }

    if (lane < 16) {
        float4 b = *(const float4*)(br + l16 * 4);
        float4 r = make_float4(acc.x + b.x, acc.y + b.y, acc.z + b.z, acc.w + b.w);
        *(float4*)(out + (size_t)node * 64 + l16 * 4) = r;
    }
}

// ---------------------------------------------------------------------------
extern "C" void kernel_launch(void* const* d_in, const int* in_sizes, int n_in,
                              void* d_out, int out_size, void* d_ws, size_t ws_size,
                              hipStream_t stream) {
    const float* h    = (const float*)d_in[0];
    const float* dvec = (const float*)d_in[1];
    const int*   src  = (const int*)  d_in[2];
    const int*   dst  = (const int*)  d_in[3];
    const float* Wl   = (const float*)d_in[4];
    const float* bl   = (const float*)d_in[5];
    const float* Wh   = (const float*)d_in[6];
    const float* bh   = (const float*)d_in[7];
    const float* Wr   = (const float*)d_in[8];
    const float* br   = (const float*)d_in[9];
    float* out = (float*)d_out;

    char* ws = (char*)d_ws;
    size_t off = 0;
    auto alloc = [&](size_t bytes) { char* p = ws + off; off += (bytes + 15) & ~size_t(15); return p; };

    float*  u_low     = (float*) alloc((size_t)N_NODES * 64 * 4);
    float*  u_high    = (float*) alloc((size_t)N_NODES * 64 * 4);
    float4* g4        = (float4*)alloc((size_t)N_NODES * 16);
    int*    count     = (int*)   alloc((size_t)N_NODES * 4);
    int*    offs      = (int*)   alloc((size_t)(N_NODES + 1) * 4);
    int*    cursor    = (int*)   alloc((size_t)N_NODES * 4);
    int*    chunksum  = (int*)   alloc(512 * 4);
    int*    chunkbase = (int*)   alloc(512 * 4);
    int*    esrc      = (int*)   alloc((size_t)N_EDGES * 4);

    int nblk_nodes = (N_NODES + 255) / 256;   // 391
    int nblk_edges = (N_EDGES + 255) / 256;   // 6250

    zero_counts_kernel<<<nblk_nodes, 256, 0, stream>>>(count);
    node_proj_kernel<<<nblk_nodes, 256, 0, stream>>>(h, Wl, Wh, Wr, u_low, u_high, g4);
    hist_kernel<<<nblk_edges, 256, 0, stream>>>(dst, count);
    chunk_sum_kernel<<<nblk_nodes, 256, 0, stream>>>(count, chunksum);
    chunk_scan_kernel<<<1, 512, 0, stream>>>(chunksum, chunkbase);
    local_scan_kernel<<<nblk_nodes, 256, 0, stream>>>(count, chunkbase, offs, cursor);
    scatter_kernel<<<nblk_edges, 256, 0, stream>>>(src, dst, cursor, esrc);
    gather_kernel<<<(N_NODES + 3) / 4, 256, 0, stream>>>(
        offs, esrc, g4, dvec, u_low, u_high, bl, bh, br, out);
}

// Round 3
// 441.363 us; speedup vs baseline: 4.4008x; 1.0794x over previous
//
#include <hip/hip_runtime.h>
#include <math.h>

#define N_NODES 100000
#define D_DIM   64
#define N_EDGES 1600000
#define P_L 0.5f
#define P_H 0.5f
#define N_CHUNKS ((N_NODES + 255) / 256)

typedef unsigned int uint;
typedef unsigned short ushort_t;

__device__ inline ushort_t f2bf(float f) {
    uint u = __float_as_uint(f);
    uint r = (u + 0x7fffu + ((u >> 16) & 1u)) >> 16;
    return (ushort_t)r;
}
__device__ inline float bf2f(uint u) { return __uint_as_float(u << 16); }

// fast tanh for x >= 0
__device__ inline float tanh_pos(float x) {
    return 1.f - 2.f / (__expf(2.f * x) + 1.f);
}

// ---------------------------------------------------------------------------
// K0: transpose Wr [64c][128k] -> wrt [128k][64c]  (one block)
// ---------------------------------------------------------------------------
__global__ __launch_bounds__(256) void transpose_wr_kernel(const float* __restrict__ Wr,
                                                           float* __restrict__ wrt) {
    for (int idx = threadIdx.x; idx < 64 * 128; idx += 256) {
        int c = idx >> 7;
        int k = idx & 127;
        wrt[k * 64 + c] = Wr[idx];
    }
}

// ---------------------------------------------------------------------------
// K1: zero degree counts
// ---------------------------------------------------------------------------
__global__ __launch_bounds__(256) void zero_counts_kernel(int* __restrict__ count) {
    int i = blockIdx.x * 256 + threadIdx.x;
    if (i < N_NODES) count[i] = 0;
}

// ---------------------------------------------------------------------------
// K2: per-node gates + h -> bf16.  One wave per node.
//   gdst4[n] = (h.Wl[:64], h.Wh[:64], d[n], 0)
//   gsrc4[n] = (h.Wl[64:], h.Wh[64:], d[n], 0)
// ---------------------------------------------------------------------------
__global__ __launch_bounds__(256) void node_gates_kernel(
    const float* __restrict__ h, const float* __restrict__ dvec,
    const float* __restrict__ Wl, const float* __restrict__ Wh,
    ushort_t* __restrict__ hbf,
    float4* __restrict__ gdst4, float4* __restrict__ gsrc4)
{
    int tid = threadIdx.x;
    int node = blockIdx.x * 4 + (tid >> 6);
    if (node >= N_NODES) return;
    int lane = tid & 63;

    float hv = h[(size_t)node * 64 + lane];
    hbf[(size_t)node * 64 + lane] = f2bf(hv);

    float pld = hv * Wl[lane];
    float pls = hv * Wl[64 + lane];
    float phd = hv * Wh[lane];
    float phs = hv * Wh[64 + lane];
    #pragma unroll
    for (int m = 32; m >= 1; m >>= 1) {
        pld += __shfl_xor(pld, m);
        pls += __shfl_xor(pls, m);
        phd += __shfl_xor(phd, m);
        phs += __shfl_xor(phs, m);
    }
    if (lane == 0) {
        float d = dvec[node];
        gdst4[node] = make_float4(pld, phd, d, 0.f);
        gsrc4[node] = make_float4(pls, phs, d, 0.f);
    }
}

// ---------------------------------------------------------------------------
// K3: histogram of dst
// ---------------------------------------------------------------------------
__global__ __launch_bounds__(256) void hist_kernel(const int* __restrict__ dst,
                                                   int* __restrict__ count) {
    int e = blockIdx.x * 256 + threadIdx.x;
    if (e < N_EDGES) atomicAdd(&count[dst[e]], 1);
}

// ---------------------------------------------------------------------------
// K4a: per-256-chunk sums
// ---------------------------------------------------------------------------
__global__ __launch_bounds__(256) void chunk_sum_kernel(const int* __restrict__ count,
                                                        int* __restrict__ chunksum) {
    __shared__ int sdata[256];
    int t = threadIdx.x;
    int i = blockIdx.x * 256 + t;
    int v = (i < N_NODES) ? count[i] : 0;
    sdata[t] = v;
    __syncthreads();
    #pragma unroll
    for (int s = 128; s >= 1; s >>= 1) {
        if (t < s) sdata[t] += sdata[t + s];
        __syncthreads();
    }
    if (t == 0) chunksum[blockIdx.x] = sdata[0];
}

// ---------------------------------------------------------------------------
// K4b: exclusive scan of chunk sums, single block
// ---------------------------------------------------------------------------
__global__ __launch_bounds__(512) void chunk_scan_kernel(const int* __restrict__ chunksum,
                                                         int* __restrict__ chunkbase) {
    __shared__ int sdata[512];
    int t = threadIdx.x;
    int v = (t < N_CHUNKS) ? chunksum[t] : 0;
    sdata[t] = v;
    __syncthreads();
    #pragma unroll
    for (int d = 1; d < 512; d <<= 1) {
        int x = (t >= d) ? sdata[t - d] : 0;
        __syncthreads();
        sdata[t] += x;
        __syncthreads();
    }
    if (t < N_CHUNKS) chunkbase[t] = sdata[t] - v;
}

// ---------------------------------------------------------------------------
// K4c: local exclusive scan -> offs, cursor
// ---------------------------------------------------------------------------
__global__ __launch_bounds__(256) void local_scan_kernel(const int* __restrict__ count,
                                                         const int* __restrict__ chunkbase,
                                                         int* __restrict__ offs,
                                                         int* __restrict__ cursor) {
    __shared__ int sdata[256];
    int t = threadIdx.x;
    int i = blockIdx.x * 256 + t;
    int v = (i < N_NODES) ? count[i] : 0;
    sdata[t] = v;
    __syncthreads();
    #pragma unroll
    for (int d = 1; d < 256; d <<= 1) {
        int x = (t >= d) ? sdata[t - d] : 0;
        __syncthreads();
        sdata[t] += x;
        __syncthreads();
    }
    int excl = chunkbase[blockIdx.x] + sdata[t] - v;
    if (i < N_NODES) {
        offs[i] = excl;
        cursor[i] = excl;
        if (i == N_NODES - 1) offs[N_NODES] = excl + v;
    }
}

// ---------------------------------------------------------------------------
// K5: scatter edge -> CSR slot
// ---------------------------------------------------------------------------
__global__ __launch_bounds__(256) void scatter_kernel(const int* __restrict__ src,
                                                      const int* __restrict__ dst,
                                                      int* __restrict__ cursor,
                                                      int* __restrict__ esrc) {
    int e = blockIdx.x * 256 + threadIdx.x;
    if (e >= N_EDGES) return;
    int t = dst[e];
    int pos = atomicAdd(&cursor[t], 1);
    esrc[pos] = src[e];
}

// ---------------------------------------------------------------------------
// K6: gather. One wave per dst node; 4 subgroups of 16 lanes, one edge each;
// each lane owns 4 of the 64 dims (8 B bf16 load). Accumulates z_low/z_high.
// z layout: [node][128] bf16 (low 0..63, high 64..127)
// ---------------------------------------------------------------------------
__global__ __launch_bounds__(256) void gather_kernel(
    const int* __restrict__ offs,
    const int* __restrict__ esrc,
    const float4* __restrict__ gdst4,
    const float4* __restrict__ gsrc4,
    const ushort_t* __restrict__ hbf,
    const float* __restrict__ bl, const float* __restrict__ bh,
    ushort_t* __restrict__ z)
{
    int tid = threadIdx.x;
    int node = blockIdx.x * 4 + (tid >> 6);
    if (node >= N_NODES) return;
    int lane = tid & 63;
    int sub = lane >> 4;
    int l16 = lane & 15;

    int beg = offs[node];
    int end = offs[node + 1];

    float4 gt = gdst4[node];
    float bl0 = bl[0];
    float bh0 = bh[0];

    float4 accl = make_float4(0.f, 0.f, 0.f, 0.f);
    float4 acch = make_float4(0.f, 0.f, 0.f, 0.f);

    for (int k = beg + sub; k < end; k += 4) {
        int s = esrc[k];
        float4 gs = gsrc4[s];
        float xl = gt.x + gs.x + bl0;
        float xh = gt.y + gs.y + bh0;
        float ll = xl > 0.f ? xl : -P_L * xl;   // leaky, always >= 0
        float hh = xh > 0.f ? xh : -P_H * xh;
        float dd = gt.z * gs.z;
        float el =  tanh_pos(ll) * dd;
        float eh = -tanh_pos(hh) * dd;

        uint2 hv = *(const uint2*)(hbf + (size_t)s * 64 + l16 * 4);
        float h0 = bf2f(hv.x & 0xffffu);
        float h1 = bf2f(hv.x >> 16);
        float h2 = bf2f(hv.y & 0xffffu);
        float h3 = bf2f(hv.y >> 16);

        accl.x += el * h0; accl.y += el * h1; accl.z += el * h2; accl.w += el * h3;
        acch.x += eh * h0; acch.y += eh * h1; acch.z += eh * h2; acch.w += eh * h3;
    }

    #pragma unroll
    for (int m = 16; m <= 32; m <<= 1) {
        accl.x += __shfl_xor(accl.x, m);
        accl.y += __shfl_xor(accl.y, m);
        accl.z += __shfl_xor(accl.z, m);
        accl.w += __shfl_xor(accl.w, m);
        acch.x += __shfl_xor(acch.x, m);
        acch.y += __shfl_xor(acch.y, m);
        acch.z += __shfl_xor(acch.z, m);
        acch.w += __shfl_xor(acch.w, m);
    }

    if (lane < 16) {
        uint2 pl, ph;
        pl.x = (uint)f2bf(accl.x) | ((uint)f2bf(accl.y) << 16);
        pl.y = (uint)f2bf(accl.z) | ((uint)f2bf(accl.w) << 16);
        ph.x = (uint)f2bf(acch.x) | ((uint)f2bf(acch.y) << 16);
        ph.y = (uint)f2bf(acch.z) | ((uint)f2bf(acch.w) << 16);
        *(uint2*)(z + (size_t)node * 128 + l16 * 4)      = pl;
        *(uint2*)(z + (size_t)node * 128 + 64 + l16 * 4) = ph;
    }
}

// ---------------------------------------------------------------------------
// K7: final transform. One thread per node: out[n] = WrT' z[n] + br.
// wrt is [128k][64c]; indices are wave-uniform -> scalar loads via K$.
// ---------------------------------------------------------------------------
__global__ __launch_bounds__(256) void final_kernel(
    const ushort_t* __restrict__ z,
    const float* __restrict__ wrt,
    const float* __restrict__ br,
    float* __restrict__ out)
{
    int node = blockIdx.x * 256 + threadIdx.x;
    if (node >= N_NODES) return;

    const ushort_t* zrow = z + (size_t)node * 128;
    float acc[64];
    #pragma unroll
    for (int c = 0; c < 64; ++c) acc[c] = 0.f;

    for (int k0 = 0; k0 < 128; k0 += 8) {
        uint4 zv = *(const uint4*)(zrow + k0);
        float zf[8];
        zf[0] = bf2f(zv.x & 0xffffu); zf[1] = bf2f(zv.x >> 16);
        zf[2] = bf2f(zv.y & 0xffffu); zf[3] = bf2f(zv.y >> 16);
        zf[4] = bf2f(zv.z & 0xffffu); zf[5] = bf2f(zv.z >> 16);
        zf[6] = bf2f(zv.w & 0xffffu); zf[7] = bf2f(zv.w >> 16);
        #pragma unroll
        for (int kk = 0; kk < 8; ++kk) {
            const float* w = wrt + (size_t)(k0 + kk) * 64;  // wave-uniform
            float hk = zf[kk];
            #pragma unroll
            for (int c = 0; c < 64; ++c) acc[c] += hk * w[c];
        }
    }

    float* op = out + (size_t)node * 64;
    #pragma unroll
    for (int q = 0; q < 16; ++q) {
        *(float4*)(op + 4 * q) = make_float4(acc[4*q]   + br[4*q],
                                             acc[4*q+1] + br[4*q+1],
                                             acc[4*q+2] + br[4*q+2],
                                             acc[4*q+3] + br[4*q+3]);
    }
}

// ---------------------------------------------------------------------------
extern "C" void kernel_launch(void* const* d_in, const int* in_sizes, int n_in,
                              void* d_out, int out_size, void* d_ws, size_t ws_size,
                              hipStream_t stream) {
    const float* h    = (const float*)d_in[0];
    const float* dvec = (const float*)d_in[1];
    const int*   src  = (const int*)  d_in[2];
    const int*   dst  = (const int*)  d_in[3];
    const float* Wl   = (const float*)d_in[4];
    const float* bl   = (const float*)d_in[5];
    const float* Wh   = (const float*)d_in[6];
    const float* bh   = (const float*)d_in[7];
    const float* Wr   = (const float*)d_in[8];
    const float* br   = (const float*)d_in[9];
    float* out = (float*)d_out;

    char* ws = (char*)d_ws;
    size_t off = 0;
    auto alloc = [&](size_t bytes) { char* p = ws + off; off += (bytes + 255) & ~size_t(255); return p; };

    ushort_t* hbf      = (ushort_t*)alloc((size_t)N_NODES * 64 * 2);     // 12.8 MB
    ushort_t* zbuf     = (ushort_t*)alloc((size_t)N_NODES * 128 * 2);    // 25.6 MB
    float4*   gdst4    = (float4*)  alloc((size_t)N_NODES * 16);         // 1.6 MB
    float4*   gsrc4    = (float4*)  alloc((size_t)N_NODES * 16);         // 1.6 MB
    float*    wrt      = (float*)   alloc(64 * 128 * 4);                 // 32 KB
    int*      count    = (int*)     alloc((size_t)N_NODES * 4);
    int*      offs     = (int*)     alloc((size_t)(N_NODES + 1) * 4);
    int*      cursor   = (int*)     alloc((size_t)N_NODES * 4);
    int*      chunksum = (int*)     alloc(512 * 4);
    int*      chunkbase= (int*)     alloc(512 * 4);
    int*      esrc     = (int*)     alloc((size_t)N_EDGES * 4);          // 6.4 MB

    int nblk_nodes = (N_NODES + 255) / 256;   // 391
    int nblk_edges = (N_EDGES + 255) / 256;   // 6250
    int nblk_waves = (N_NODES + 3) / 4;       // 25000

    transpose_wr_kernel<<<1, 256, 0, stream>>>(Wr, wrt);
    zero_counts_kernel<<<nblk_nodes, 256, 0, stream>>>(count);
    node_gates_kernel<<<nblk_waves, 256, 0, stream>>>(h, dvec, Wl, Wh, hbf, gdst4, gsrc4);
    hist_kernel<<<nblk_edges, 256, 0, stream>>>(dst, count);
    chunk_sum_kernel<<<nblk_nodes, 256, 0, stream>>>(count, chunksum);
    chunk_scan_kernel<<<1, 512, 0, stream>>>(chunksum, chunkbase);
    local_scan_kernel<<<nblk_nodes, 256, 0, stream>>>(count, chunkbase, offs, cursor);
    scatter_kernel<<<nblk_edges, 256, 0, stream>>>(src, dst, cursor, esrc);
    gather_kernel<<<nblk_waves, 256, 0, stream>>>(offs, esrc, gdst4, gsrc4, hbf, bl, bh, zbuf);
    final_kernel<<<nblk_nodes, 256, 0, stream>>>(zbuf, wrt, br, out);
}